// Round 11
// baseline (312.320 us; speedup 1.0000x reference)
//
#include <hip/hip_runtime.h>
#include <hip/hip_bf16.h>

// Cross-attention: fp32 in -> fp32 out, bf16 MFMA compute.
// B=4 L=4096 R=512 DIM=1024 H=16 DH=64, scale = 1/8.
// R11: revert Q/O GEMMs to R8's proven 128^2 BK=64 structure (R9/R10's
// 8-phase 256^2 port verified but gained nothing: 307 vs 302 -- the
// template needs its full derived-wait tuning to pay at K=1024, and both
// structural GEMM attempts are now null). NEW: x fp32->bf16 conversion is
// FUSED into the Q-segment A-staging of gemm_qkv (reg-stage: global fp32
// load -> f2bf -> ds_write_b128 into the same swizzled slots). Removes the
// xb round-trip (-96 MB prep traffic, +32 MB Q-GEMM = net -64 MB HBM);
// prep shrinks to ctx+weights (5120 blocks). bf16 values are bitwise
// identical to R8's -> absmax must stay 0.002929688.
// attn byte-identical (V through LDS; R5 proved direct-global PV 3x worse).
#define DIMC 1024
#define HEADS 16
#define DHEAD 64
#define LQ 4096
#define RK 512
#define BATCH 4

// 0.125 * log2(e): folded into the Q projection so softmax runs in exp2 domain
#define QSCALE 0.18033688011112042f

using bf16x8  = __attribute__((ext_vector_type(8))) __bf16;
using short4v = __attribute__((ext_vector_type(4))) short;
using f32x4   = __attribute__((ext_vector_type(4))) float;

__device__ inline ushort f2bf(float f) {
  __hip_bfloat16 h = __float2bfloat16(f);
  return *reinterpret_cast<ushort*>(&h);
}

__device__ inline float exp2_fast(float x) {
  float r; asm("v_exp_f32 %0, %1" : "=v"(r) : "v"(x)); return r;
}

// ---------------- prep: ctx convert + weight transpose -----------------------
// bid < 1024: fp32->bf16 of ctx (2097152 elems, 8/thread).
// bid >= 1024: 32x32 transpose tiles of W0..W3 (z = (bid-1024)>>10).
__global__ __launch_bounds__(256) void prep(const float* __restrict__ ctx,
    ushort* __restrict__ ctxb,
    const float* __restrict__ W0, const float* __restrict__ W1,
    const float* __restrict__ W2, const float* __restrict__ W3,
    ushort* __restrict__ D0, ushort* __restrict__ D1,
    ushort* __restrict__ D2, ushort* __restrict__ D3) {
  __shared__ ushort tile[32][33];
  const int bid = blockIdx.x;
  if (bid < 1024) {
    size_t i = ((size_t)bid * 256 + threadIdx.x) * 8;
    float4 a = *(const float4*)(ctx + i);
    float4 b = *(const float4*)(ctx + i + 4);
    ushort u[8];
    u[0]=f2bf(a.x); u[1]=f2bf(a.y); u[2]=f2bf(a.z); u[3]=f2bf(a.w);
    u[4]=f2bf(b.x); u[5]=f2bf(b.y); u[6]=f2bf(b.z); u[7]=f2bf(b.w);
    *(uint4*)(ctxb + i) = *(const uint4*)u;
    return;
  }
  const int tb = bid - 1024;            // 0..4095
  const int z = tb >> 10, rem = tb & 1023;
  const int bx = rem & 31, by = rem >> 5;
  const float* src = (z == 0) ? W0 : (z == 1) ? W1 : (z == 2) ? W2 : W3;
  ushort* dst = (z == 0) ? D0 : (z == 1) ? D1 : (z == 2) ? D2 : D3;
  const int tx = threadIdx.x & 31, ty = threadIdx.x >> 5; // 32 x 8
  const int xg = bx * 32 + tx;
  #pragma unroll
  for (int j = 0; j < 32; j += 8)
    tile[ty + j][tx] = f2bf(src[(size_t)(by * 32 + ty + j) * DIMC + xg]);
  __syncthreads();
  const int xo = by * 32 + tx;
  #pragma unroll
  for (int j = 0; j < 32; j += 8)
    dst[(size_t)(bx * 32 + ty + j) * DIMC + xo] = tile[tx][ty + j];
}

// ---------------- fused Q + KV projection GEMM (BK=64, swizzled LDS) ---------
// grid (8, 160): by<128 -> Q segment: A = x fp32 DIRECT (reg-staged convert
// into LDS -- no xb roundtrip), Bt=WqT, out Qw bf16 * QSCALE.
// by>=128 -> KV segment (A=ctxb bf16 via gload_lds): n<1024 -> K into Kw;
// n>=1024 -> V transposed per (b,h): Vt[((b*16+h)*64+dh)*512 + r].
// Per-segment bijective XCD swizzle; launch_bounds(256,4) -> 4 blocks/CU.
__global__ __launch_bounds__(256, 4) void gemm_qkv(const float* __restrict__ X,
    const ushort* __restrict__ ctxb, const ushort* __restrict__ WqT,
    const ushort* __restrict__ WkvT, ushort* __restrict__ Qw,
    ushort* __restrict__ Kw, ushort* __restrict__ Vt) {
  __shared__ ushort As[128 * 64];
  __shared__ ushort Bs[128 * 64];
  const int tid  = threadIdx.x;
  const int wave = tid >> 6, lane = tid & 63;
  const int lr = lane & 15, quad = lane >> 4;
  const ushort* Bt; size_t m0, n0; int seg;
  if (blockIdx.y < 128) {               // Q: 1024 wgs
    int bid = blockIdx.y * 8 + blockIdx.x;
    int swz = (bid & 7) * 128 + (bid >> 3);
    m0 = (size_t)(swz >> 3) * 128;      // 0..16383
    n0 = (size_t)(swz & 7) * 128;       // 0..1023
    Bt = WqT; seg = 0;
  } else {                              // KV: 256 wgs
    int bid = (blockIdx.y - 128) * 8 + blockIdx.x;   // 0..255
    int swz = (bid & 7) * 32 + (bid >> 3);
    m0 = (size_t)(swz >> 4) * 128;      // 0..2047
    n0 = (size_t)(swz & 15) * 128;      // 0..2047
    Bt = WkvT; seg = 1;
  }
  const int wm = (wave >> 1) * 64, wn = (wave & 1) * 64;
  const int rsw = lr & 7;               // read-side swizzle (chunk units)
  f32x4 acc[4][4] = {};
  for (int k0 = 0; k0 < DIMC; k0 += 64) {
    __syncthreads();
    #pragma unroll
    for (int t = 0; t < 4; ++t) {
      int c = (wave * 4 + t) * 64 + lane;   // [0,1024) chunks of 8 elems
      int row = c >> 3, cc = c & 7;
      int col = (cc ^ (row & 7)) * 8;       // pre-swizzled source column
      // B always bf16 via global_load_lds (linear dest)
      const ushort* gb = Bt + (n0 + row) * DIMC + k0 + col;
      __builtin_amdgcn_global_load_lds(
          (__attribute__((address_space(1))) void*)gb,
          (__attribute__((address_space(3))) void*)(Bs + (size_t)(wave * 4 + t) * 512),
          16, 0, 0);
      if (seg == 1) {
        const ushort* ga = ctxb + (m0 + row) * DIMC + k0 + col;
        __builtin_amdgcn_global_load_lds(
            (__attribute__((address_space(1))) void*)ga,
            (__attribute__((address_space(3))) void*)(As + (size_t)(wave * 4 + t) * 512),
            16, 0, 0);
      } else {
        // Q segment: A = x fp32, convert in-flight (same values as R8's xb)
        const float* gx = X + (m0 + row) * DIMC + k0 + col;
        float4 f0 = *(const float4*)gx;
        float4 f1 = *(const float4*)(gx + 4);
        ushort u[8];
        u[0]=f2bf(f0.x); u[1]=f2bf(f0.y); u[2]=f2bf(f0.z); u[3]=f2bf(f0.w);
        u[4]=f2bf(f1.x); u[5]=f2bf(f1.y); u[6]=f2bf(f1.z); u[7]=f2bf(f1.w);
        *(uint4*)(As + (size_t)(wave * 4 + t) * 512 + lane * 8) =
            *(const uint4*)u;
      }
    }
    __syncthreads();
    #pragma unroll
    for (int ks = 0; ks < 2; ++ks) {
      bf16x8 af[4], bfr[4];
      #pragma unroll
      for (int mt = 0; mt < 4; ++mt)
        af[mt] = *(const bf16x8*)(As + (wm + mt * 16 + lr) * 64
                                     + (((ks * 4 + quad) ^ rsw) * 8));
      #pragma unroll
      for (int nt = 0; nt < 4; ++nt)
        bfr[nt] = *(const bf16x8*)(Bs + (wn + nt * 16 + lr) * 64
                                      + (((ks * 4 + quad) ^ rsw) * 8));
      #pragma unroll
      for (int mt = 0; mt < 4; ++mt)
        #pragma unroll
        for (int nt = 0; nt < 4; ++nt)
          acc[mt][nt] = __builtin_amdgcn_mfma_f32_16x16x32_bf16(
              af[mt], bfr[nt], acc[mt][nt], 0, 0, 0);
    }
  }
  // C/D layout: n = lane&15, m = quad*4 + reg
  if (seg == 0) {
    #pragma unroll
    for (int mt = 0; mt < 4; ++mt)
      #pragma unroll
      for (int nt = 0; nt < 4; ++nt)
        #pragma unroll
        for (int j = 0; j < 4; ++j) {
          size_t m = m0 + wm + mt * 16 + quad * 4 + j;
          size_t n = n0 + wn + nt * 16 + lr;
          Qw[m * DIMC + n] = f2bf(acc[mt][nt][j] * QSCALE);
        }
  } else if (n0 < 1024) {
    #pragma unroll
    for (int mt = 0; mt < 4; ++mt)
      #pragma unroll
      for (int nt = 0; nt < 4; ++nt)
        #pragma unroll
        for (int j = 0; j < 4; ++j) {
          size_t m = m0 + wm + mt * 16 + quad * 4 + j;
          size_t n = n0 + wn + nt * 16 + lr;
          Kw[m * DIMC + n] = f2bf(acc[mt][nt][j]);
        }
  } else {
    // V half: write transposed V^T[b][h][dh][r]
    #pragma unroll
    for (int mt = 0; mt < 4; ++mt)
      #pragma unroll
      for (int nt = 0; nt < 4; ++nt) {
        size_t m = m0 + wm + mt * 16 + quad * 4;       // r base (4-aligned)
        int hcol = (int)(n0 + wn + nt * 16 + lr) - 1024;
        int h = hcol >> 6, dh = hcol & 63;
        int bb = (int)(m >> 9), r = (int)(m & 511);
        ushort o4[4];
        #pragma unroll
        for (int j = 0; j < 4; ++j) o4[j] = f2bf(acc[mt][nt][j]);
        *(ushort4*)(Vt + (((size_t)bb * HEADS + h) * 64 + dh) * RK + r) =
            *(const ushort4*)o4;
      }
  }
}

// ---------------- O-projection GEMM (fp32 out, BK=64, swizzled LDS) ----------
__global__ __launch_bounds__(256, 4) void gemm_bt(const ushort* __restrict__ A,
    const ushort* __restrict__ Bt, float* __restrict__ C32) {
  __shared__ ushort As[128 * 64];
  __shared__ ushort Bs[128 * 64];
  const int tid  = threadIdx.x;
  const int wave = tid >> 6, lane = tid & 63;
  const int lr = lane & 15, quad = lane >> 4;
  const int nbx = gridDim.x;
  const int bid = blockIdx.y * nbx + blockIdx.x;
  const int cpx = (nbx * gridDim.y) >> 3;
  const int swz = (bid & 7) * cpx + (bid >> 3);
  const int bx = swz % nbx, by = swz / nbx;
  const size_t m0 = (size_t)by * 128;
  const size_t n0 = (size_t)bx * 128;
  const int wm = (wave >> 1) * 64, wn = (wave & 1) * 64;
  const int rsw = lr & 7;
  f32x4 acc[4][4] = {};
  for (int k0 = 0; k0 < DIMC; k0 += 64) {
    __syncthreads();
    #pragma unroll
    for (int t = 0; t < 4; ++t) {
      int c = (wave * 4 + t) * 64 + lane;
      int row = c >> 3, cc = c & 7;
      int col = (cc ^ (row & 7)) * 8;
      const ushort* ga = A  + (m0 + row) * DIMC + k0 + col;
      const ushort* gb = Bt + (n0 + row) * DIMC + k0 + col;
      __builtin_amdgcn_global_load_lds(
          (__attribute__((address_space(1))) void*)ga,
          (__attribute__((address_space(3))) void*)(As + (size_t)(wave * 4 + t) * 512),
          16, 0, 0);
      __builtin_amdgcn_global_load_lds(
          (__attribute__((address_space(1))) void*)gb,
          (__attribute__((address_space(3))) void*)(Bs + (size_t)(wave * 4 + t) * 512),
          16, 0, 0);
    }
    __syncthreads();
    #pragma unroll
    for (int ks = 0; ks < 2; ++ks) {
      bf16x8 af[4], bfr[4];
      #pragma unroll
      for (int mt = 0; mt < 4; ++mt)
        af[mt] = *(const bf16x8*)(As + (wm + mt * 16 + lr) * 64
                                     + (((ks * 4 + quad) ^ rsw) * 8));
      #pragma unroll
      for (int nt = 0; nt < 4; ++nt)
        bfr[nt] = *(const bf16x8*)(Bs + (wn + nt * 16 + lr) * 64
                                      + (((ks * 4 + quad) ^ rsw) * 8));
      #pragma unroll
      for (int mt = 0; mt < 4; ++mt)
        #pragma unroll
        for (int nt = 0; nt < 4; ++nt)
          acc[mt][nt] = __builtin_amdgcn_mfma_f32_16x16x32_bf16(
              af[mt], bfr[nt], acc[mt][nt], 0, 0, 0);
    }
  }
  #pragma unroll
  for (int mt = 0; mt < 4; ++mt)
    #pragma unroll
    for (int nt = 0; nt < 4; ++nt)
      #pragma unroll
      for (int j = 0; j < 4; ++j) {
        size_t m = m0 + wm + mt * 16 + quad * 4 + j;
        size_t n = n0 + wn + nt * 16 + lr;
        C32[m * DIMC + n] = acc[mt][nt][j];
      }
}

// ---------------- fused flash attention (S^T trick) --------------------------
// (byte-identical to R6-R10 -- proven structure)
__global__ __launch_bounds__(256) void attn(ushort* __restrict__ QO,
    const ushort* __restrict__ K, const ushort* __restrict__ Vt) {
  __shared__ __align__(16) ushort Ks[128 * 64];
  __shared__ __align__(16) ushort Vs[64 * 128];
  const int tid  = threadIdx.x;
  const int wave = tid >> 6, lane = tid & 63;
  const int lr = lane & 15, quad = lane >> 4;
  const int b = blockIdx.z, h = blockIdx.y, qb = blockIdx.x;
  const int lsw = (lr & 7) << 3;

  bf16x8 bq[2];
  {
    size_t row = (size_t)b * LQ + qb * 64 + wave * 16 + lr;
    const ushort* qp = QO + row * DIMC + h * DHEAD + quad * 8;
    bq[0] = *(const bf16x8*)(qp);
    bq[1] = *(const bf16x8*)(qp + 32);
  }

  const int krow = tid >> 3, kcol = (tid & 7) * 8;
  const int vrow = tid >> 4, vcol = (tid & 15) * 8;
  const int kwsw = (krow & 7) << 3;
  const int vwsw = (vrow & 7) << 3;
  const ushort* Kbase = K  + ((size_t)b * RK) * DIMC + h * DHEAD;
  const ushort* Vbase = Vt + (((size_t)b * HEADS + h) * 64) * RK;

  uint4 kr0, kr1, kr2, kr3, vr0, vr1, vr2, vr3;
#define LOADK(rc_, i_) \
  (*(const uint4*)(Kbase + (size_t)((rc_) * 128 + (i_) * 32 + krow) * DIMC + kcol))
#define LOADV(rc_, i_) \
  (*(const uint4*)(Vbase + (size_t)((i_) * 16 + vrow) * RK + (rc_) * 128 + vcol))
#define ISSUE(rc_) do {                                      \
    kr0 = LOADK(rc_, 0); kr1 = LOADK(rc_, 1);                \
    kr2 = LOADK(rc_, 2); kr3 = LOADK(rc_, 3);                \
    vr0 = LOADV(rc_, 0); vr1 = LOADV(rc_, 1);                \
    vr2 = LOADV(rc_, 2); vr3 = LOADV(rc_, 3);                \
  } while (0)

  ISSUE(0);

  float mi = -1e30f, li = 0.f;
  f32x4 o[4] = {};

  for (int rc = 0; rc < 4; ++rc) {
    __syncthreads();
    *(uint4*)(Ks + ((((0 * 32 + krow) * 64) + kcol) ^ kwsw)) = kr0;
    *(uint4*)(Ks + ((((1 * 32 + krow) * 64) + kcol) ^ kwsw)) = kr1;
    *(uint4*)(Ks + ((((2 * 32 + krow) * 64) + kcol) ^ kwsw)) = kr2;
    *(uint4*)(Ks + ((((3 * 32 + krow) * 64) + kcol) ^ kwsw)) = kr3;
    *(uint4*)(Vs + ((((0 * 16 + vrow) * 128) + vcol) ^ vwsw)) = vr0;
    *(uint4*)(Vs + ((((1 * 16 + vrow) * 128) + vcol) ^ vwsw)) = vr1;
    *(uint4*)(Vs + ((((2 * 16 + vrow) * 128) + vcol) ^ vwsw)) = vr2;
    *(uint4*)(Vs + ((((3 * 16 + vrow) * 128) + vcol) ^ vwsw)) = vr3;
    __syncthreads();
    if (rc < 3) ISSUE(rc + 1);

    float s[8][4];
    __builtin_amdgcn_s_setprio(1);
    #pragma unroll
    for (int nt = 0; nt < 8; ++nt) {
      f32x4 acc = {};
      acc = __builtin_amdgcn_mfma_f32_16x16x32_bf16(
          *(const bf16x8*)(Ks + ((((nt * 16 + lr) * 64) + quad * 8) ^ lsw)),
          bq[0], acc, 0, 0, 0);
      acc = __builtin_amdgcn_mfma_f32_16x16x32_bf16(
          *(const bf16x8*)(Ks + ((((nt * 16 + lr) * 64) + quad * 8 + 32) ^ lsw)),
          bq[1], acc, 0, 0, 0);
      #pragma unroll
      for (int j = 0; j < 4; ++j) s[nt][j] = acc[j];
    }
    __builtin_amdgcn_s_setprio(0);

    float c0 = s[0][0], c1 = s[0][1], c2 = s[0][2], c3 = s[0][3];
    #pragma unroll
    for (int nt = 1; nt < 8; ++nt) {
      c0 = fmaxf(c0, s[nt][0]); c1 = fmaxf(c1, s[nt][1]);
      c2 = fmaxf(c2, s[nt][2]); c3 = fmaxf(c3, s[nt][3]);
    }
    float cm = fmaxf(fmaxf(c0, c1), fmaxf(c2, c3));
    cm = fmaxf(cm, __shfl_xor(cm, 16));
    cm = fmaxf(cm, __shfl_xor(cm, 32));

    if (!__all(cm - mi <= 8.f)) {
      float mnew = fmaxf(mi, cm);
      float alpha = exp2_fast(mi - mnew);
      mi = mnew;
      li *= alpha;
      float a_bc[4];
      #pragma unroll
      for (int j = 0; j < 4; ++j) a_bc[j] = __shfl(alpha, quad * 4 + j, 16);
      #pragma unroll
      for (int n2 = 0; n2 < 4; ++n2)
        #pragma unroll
        for (int j = 0; j < 4; ++j) o[n2][j] *= a_bc[j];
    }

    short4v pf[8];
    float r0 = 0.f, r1 = 0.f, r2 = 0.f, r3 = 0.f;
    #pragma unroll
    for (int nt = 0; nt < 8; ++nt) {
      float p0 = exp2_fast(s[nt][0] - mi);
      float p1 = exp2_fast(s[nt][1] - mi);
      float p2 = exp2_fast(s[nt][2] - mi);
      float p3 = exp2_fast(s[nt][3] - mi);
      r0 += p0; r1 += p1; r2 += p2; r3 += p3;
      pf[nt][0] = (short)f2bf(p0); pf[nt][1] = (short)f2bf(p1);
      pf[nt][2] = (short)f2bf(p2); pf[nt][3] = (short)f2bf(p3);
    }
    float rs = (r0 + r1) + (r2 + r3);
    rs += __shfl_xor(rs, 16);
    rs += __shfl_xor(rs, 32);
    li += rs;

    __builtin_amdgcn_s_setprio(1);
    #pragma unroll
    for (int kt = 0; kt < 8; ++kt)
      #pragma unroll
      for (int n2 = 0; n2 < 4; ++n2) {
        short4v bv = *(const short4v*)(
            Vs + ((((n2 * 16 + lr) * 128) + kt * 16 + quad * 4) ^ lsw));
        o[n2] = __builtin_amdgcn_mfma_f32_16x16x16bf16_1k(pf[kt], bv, o[n2], 0, 0, 0);
      }
    __builtin_amdgcn_s_setprio(0);
  }
#undef LOADK
#undef LOADV
#undef ISSUE

  float li_bc[4];
  #pragma unroll
  for (int j = 0; j < 4; ++j) li_bc[j] = __shfl(li, quad * 4 + j, 16);
  #pragma unroll
  for (int n2 = 0; n2 < 4; ++n2)
    #pragma unroll
    for (int j = 0; j < 4; ++j) {
      size_t row = (size_t)b * LQ + qb * 64 + wave * 16 + quad * 4 + j;
      QO[row * DIMC + h * DHEAD + n2 * 16 + lr] = f2bf(o[n2][j] / li_bc[j]);
    }
}

// ---------------- launch -----------------------------------------------------
extern "C" void kernel_launch(void* const* d_in, const int* in_sizes, int n_in,
                              void* d_out, int out_size, void* d_ws, size_t ws_size,
                              hipStream_t stream) {
  const float* x   = (const float*)d_in[0];
  const float* ctx = (const float*)d_in[1];

  // d_out scratch (fp32 out buffer = 67 MB; all dead before final GEMM).
  // xb slot no longer used (x is consumed fp32-direct by gemm_qkv).
  ushort* outs = (ushort*)d_out;
  ushort* ctxb = outs + (size_t)16777216;            //  2097152
  ushort* WqT  = outs + (size_t)18874368;            //  1048576
  ushort* WkT  = outs + (size_t)19922944;            //  1048576 (WvT contiguous)
  ushort* WvT  = outs + (size_t)20971520;            //  1048576
  ushort* Kw   = outs + (size_t)22020096;            //  2097152
  ushort* Vt_g = outs + (size_t)24117248;            //  2097152

  // ws: Qw (33.5 MB) | WoT (2.1 MB)
  ushort* ws  = (ushort*)d_ws;
  ushort* Qw  = ws;
  ushort* WoT = ws + (size_t)16384 * 1024;

  prep<<<5120, 256, 0, stream>>>(ctx, ctxb,
      (const float*)d_in[2], (const float*)d_in[3], (const float*)d_in[4],
      (const float*)d_in[5], WqT, WkT, WvT, WoT);
  gemm_qkv<<<dim3(8, 160), 256, 0, stream>>>(x, ctxb, WqT, WkT, Qw, Kw, Vt_g);
  attn<<<dim3(LQ / 64, HEADS, BATCH), 256, 0, stream>>>(Qw, Kw, Vt_g);
  gemm_bt<<<dim3(8, 128), 256, 0, stream>>>(Qw, WoT, (float*)d_out);
}

// Round 12
// 299.297 us; speedup vs baseline: 1.0435x; 1.0435x over previous
//
#include <hip/hip_runtime.h>
#include <hip/hip_bf16.h>

// Cross-attention: fp32 in -> fp32 out, bf16 MFMA compute.
// B=4 L=4096 R=512 DIM=1024 H=16 DH=64, scale = 1/8.
// R12: revert pipeline to R8 (proven best 302.2: prep converts x+ctx, GEMMs
// all global_load_lds -- R11's fused reg-staging exposed HBM latency inside
// the barrier interval, same error class as R5). NEW in attn: softmax
// denominator moved VALU -> MFMA via a ones-column PV tile: o[4] =
// mfma(pf, ones) accumulates row-sums in [q=quad*4+j] layout. Removes
// 32 adds + 2 shfl + li bookkeeping per rc and the final li shfl;
// normalize is lane-local o[n2][j]/o[4][j]. Denominator now uses the SAME
// bf16 P as the numerator (consistent). +8 MFMA/rc on the idle matrix pipe.
#define DIMC 1024
#define HEADS 16
#define DHEAD 64
#define LQ 4096
#define RK 512
#define BATCH 4

// 0.125 * log2(e): folded into the Q projection so softmax runs in exp2 domain
#define QSCALE 0.18033688011112042f

using bf16x8  = __attribute__((ext_vector_type(8))) __bf16;
using short4v = __attribute__((ext_vector_type(4))) short;
using f32x4   = __attribute__((ext_vector_type(4))) float;

__device__ inline ushort f2bf(float f) {
  __hip_bfloat16 h = __float2bfloat16(f);
  return *reinterpret_cast<ushort*>(&h);
}

__device__ inline float exp2_fast(float x) {
  float r; asm("v_exp_f32 %0, %1" : "=v"(r) : "v"(x)); return r;
}

// ---------------- prep: cvt_in + transpose_w merged --------------------------
// bid < 9216: fp32->bf16 of x (16777216) then ctx (2097152), 8 elems/thread.
// bid >= 9216: 32x32 transpose tiles of W0..W3 (z = (bid-9216)>>10).
__global__ __launch_bounds__(256) void prep(const float* __restrict__ x,
    const float* __restrict__ ctx, ushort* __restrict__ xb,
    ushort* __restrict__ ctxb,
    const float* __restrict__ W0, const float* __restrict__ W1,
    const float* __restrict__ W2, const float* __restrict__ W3,
    ushort* __restrict__ D0, ushort* __restrict__ D1,
    ushort* __restrict__ D2, ushort* __restrict__ D3) {
  __shared__ ushort tile[32][33];
  const int bid = blockIdx.x;
  if (bid < 9216) {
    size_t i = ((size_t)bid * 256 + threadIdx.x) * 8;
    const float* src; ushort* dst; size_t off;
    if (i < (size_t)16777216) { src = x; dst = xb; off = i; }
    else { src = ctx; dst = ctxb; off = i - 16777216; }
    float4 a = *(const float4*)(src + off);
    float4 b = *(const float4*)(src + off + 4);
    ushort u[8];
    u[0]=f2bf(a.x); u[1]=f2bf(a.y); u[2]=f2bf(a.z); u[3]=f2bf(a.w);
    u[4]=f2bf(b.x); u[5]=f2bf(b.y); u[6]=f2bf(b.z); u[7]=f2bf(b.w);
    *(uint4*)(dst + off) = *(const uint4*)u;
    return;
  }
  const int tb = bid - 9216;            // 0..4095
  const int z = tb >> 10, rem = tb & 1023;
  const int bx = rem & 31, by = rem >> 5;
  const float* src = (z == 0) ? W0 : (z == 1) ? W1 : (z == 2) ? W2 : W3;
  ushort* dst = (z == 0) ? D0 : (z == 1) ? D1 : (z == 2) ? D2 : D3;
  const int tx = threadIdx.x & 31, ty = threadIdx.x >> 5; // 32 x 8
  const int xg = bx * 32 + tx;
  #pragma unroll
  for (int j = 0; j < 32; j += 8)
    tile[ty + j][tx] = f2bf(src[(size_t)(by * 32 + ty + j) * DIMC + xg]);
  __syncthreads();
  const int xo = by * 32 + tx;
  #pragma unroll
  for (int j = 0; j < 32; j += 8)
    dst[(size_t)(bx * 32 + ty + j) * DIMC + xo] = tile[tx][ty + j];
}

// ---------------- fused Q + KV projection GEMM (BK=64, swizzled LDS) ---------
// grid (8, 160): by<128 -> Q segment (16384x1024, out Qw bf16 * QSCALE);
// by>=128 -> KV segment (2048x2048): n<1024 -> K into Kw; n>=1024 -> V
// transposed per (b,h): Vt[((b*16+h)*64+dh)*512 + r]. Per-segment XCD swizzle.
__global__ __launch_bounds__(256, 4) void gemm_qkv(const ushort* __restrict__ xb,
    const ushort* __restrict__ ctxb, const ushort* __restrict__ WqT,
    const ushort* __restrict__ WkvT, ushort* __restrict__ Qw,
    ushort* __restrict__ Kw, ushort* __restrict__ Vt) {
  __shared__ ushort As[128 * 64];
  __shared__ ushort Bs[128 * 64];
  const int tid  = threadIdx.x;
  const int wave = tid >> 6, lane = tid & 63;
  const int lr = lane & 15, quad = lane >> 4;
  const ushort* A; const ushort* Bt; size_t m0, n0; int seg;
  if (blockIdx.y < 128) {               // Q: 1024 wgs
    int bid = blockIdx.y * 8 + blockIdx.x;
    int swz = (bid & 7) * 128 + (bid >> 3);
    m0 = (size_t)(swz >> 3) * 128;      // 0..16383
    n0 = (size_t)(swz & 7) * 128;       // 0..1023
    A = xb; Bt = WqT; seg = 0;
  } else {                              // KV: 256 wgs
    int bid = (blockIdx.y - 128) * 8 + blockIdx.x;   // 0..255
    int swz = (bid & 7) * 32 + (bid >> 3);
    m0 = (size_t)(swz >> 4) * 128;      // 0..2047
    n0 = (size_t)(swz & 15) * 128;      // 0..2047
    A = ctxb; Bt = WkvT; seg = 1;
  }
  const int wm = (wave >> 1) * 64, wn = (wave & 1) * 64;
  const int rsw = lr & 7;               // read-side swizzle (chunk units)
  f32x4 acc[4][4] = {};
  for (int k0 = 0; k0 < DIMC; k0 += 64) {
    __syncthreads();
    #pragma unroll
    for (int t = 0; t < 4; ++t) {
      int c = (wave * 4 + t) * 64 + lane;   // [0,1024) chunks of 8 bf16
      int row = c >> 3, cc = c & 7;
      int col = (cc ^ (row & 7)) * 8;       // pre-swizzled global source
      const ushort* ga = A  + (m0 + row) * DIMC + k0 + col;
      const ushort* gb = Bt + (n0 + row) * DIMC + k0 + col;
      __builtin_amdgcn_global_load_lds(
          (__attribute__((address_space(1))) void*)ga,
          (__attribute__((address_space(3))) void*)(As + (size_t)(wave * 4 + t) * 512),
          16, 0, 0);
      __builtin_amdgcn_global_load_lds(
          (__attribute__((address_space(1))) void*)gb,
          (__attribute__((address_space(3))) void*)(Bs + (size_t)(wave * 4 + t) * 512),
          16, 0, 0);
    }
    __syncthreads();
    #pragma unroll
    for (int ks = 0; ks < 2; ++ks) {
      bf16x8 af[4], bfr[4];
      #pragma unroll
      for (int mt = 0; mt < 4; ++mt)
        af[mt] = *(const bf16x8*)(As + (wm + mt * 16 + lr) * 64
                                     + (((ks * 4 + quad) ^ rsw) * 8));
      #pragma unroll
      for (int nt = 0; nt < 4; ++nt)
        bfr[nt] = *(const bf16x8*)(Bs + (wn + nt * 16 + lr) * 64
                                      + (((ks * 4 + quad) ^ rsw) * 8));
      #pragma unroll
      for (int mt = 0; mt < 4; ++mt)
        #pragma unroll
        for (int nt = 0; nt < 4; ++nt)
          acc[mt][nt] = __builtin_amdgcn_mfma_f32_16x16x32_bf16(
              af[mt], bfr[nt], acc[mt][nt], 0, 0, 0);
    }
  }
  // C/D layout: n = lane&15, m = quad*4 + reg
  if (seg == 0) {
    #pragma unroll
    for (int mt = 0; mt < 4; ++mt)
      #pragma unroll
      for (int nt = 0; nt < 4; ++nt)
        #pragma unroll
        for (int j = 0; j < 4; ++j) {
          size_t m = m0 + wm + mt * 16 + quad * 4 + j;
          size_t n = n0 + wn + nt * 16 + lr;
          Qw[m * DIMC + n] = f2bf(acc[mt][nt][j] * QSCALE);
        }
  } else if (n0 < 1024) {
    #pragma unroll
    for (int mt = 0; mt < 4; ++mt)
      #pragma unroll
      for (int nt = 0; nt < 4; ++nt)
        #pragma unroll
        for (int j = 0; j < 4; ++j) {
          size_t m = m0 + wm + mt * 16 + quad * 4 + j;
          size_t n = n0 + wn + nt * 16 + lr;
          Kw[m * DIMC + n] = f2bf(acc[mt][nt][j]);
        }
  } else {
    // V half: write transposed V^T[b][h][dh][r]
    #pragma unroll
    for (int mt = 0; mt < 4; ++mt)
      #pragma unroll
      for (int nt = 0; nt < 4; ++nt) {
        size_t m = m0 + wm + mt * 16 + quad * 4;       // r base (4-aligned)
        int hcol = (int)(n0 + wn + nt * 16 + lr) - 1024;
        int h = hcol >> 6, dh = hcol & 63;
        int bb = (int)(m >> 9), r = (int)(m & 511);
        ushort o4[4];
        #pragma unroll
        for (int j = 0; j < 4; ++j) o4[j] = f2bf(acc[mt][nt][j]);
        *(ushort4*)(Vt + (((size_t)bb * HEADS + h) * 64 + dh) * RK + r) =
            *(const ushort4*)o4;
      }
  }
}

// ---------------- O-projection GEMM (fp32 out, BK=64, swizzled LDS) ----------
__global__ __launch_bounds__(256, 4) void gemm_bt(const ushort* __restrict__ A,
    const ushort* __restrict__ Bt, float* __restrict__ C32) {
  __shared__ ushort As[128 * 64];
  __shared__ ushort Bs[128 * 64];
  const int tid  = threadIdx.x;
  const int wave = tid >> 6, lane = tid & 63;
  const int lr = lane & 15, quad = lane >> 4;
  const int nbx = gridDim.x;
  const int bid = blockIdx.y * nbx + blockIdx.x;
  const int cpx = (nbx * gridDim.y) >> 3;
  const int swz = (bid & 7) * cpx + (bid >> 3);
  const int bx = swz % nbx, by = swz / nbx;
  const size_t m0 = (size_t)by * 128;
  const size_t n0 = (size_t)bx * 128;
  const int wm = (wave >> 1) * 64, wn = (wave & 1) * 64;
  const int rsw = lr & 7;
  f32x4 acc[4][4] = {};
  for (int k0 = 0; k0 < DIMC; k0 += 64) {
    __syncthreads();
    #pragma unroll
    for (int t = 0; t < 4; ++t) {
      int c = (wave * 4 + t) * 64 + lane;
      int row = c >> 3, cc = c & 7;
      int col = (cc ^ (row & 7)) * 8;
      const ushort* ga = A  + (m0 + row) * DIMC + k0 + col;
      const ushort* gb = Bt + (n0 + row) * DIMC + k0 + col;
      __builtin_amdgcn_global_load_lds(
          (__attribute__((address_space(1))) void*)ga,
          (__attribute__((address_space(3))) void*)(As + (size_t)(wave * 4 + t) * 512),
          16, 0, 0);
      __builtin_amdgcn_global_load_lds(
          (__attribute__((address_space(1))) void*)gb,
          (__attribute__((address_space(3))) void*)(Bs + (size_t)(wave * 4 + t) * 512),
          16, 0, 0);
    }
    __syncthreads();
    #pragma unroll
    for (int ks = 0; ks < 2; ++ks) {
      bf16x8 af[4], bfr[4];
      #pragma unroll
      for (int mt = 0; mt < 4; ++mt)
        af[mt] = *(const bf16x8*)(As + (wm + mt * 16 + lr) * 64
                                     + (((ks * 4 + quad) ^ rsw) * 8));
      #pragma unroll
      for (int nt = 0; nt < 4; ++nt)
        bfr[nt] = *(const bf16x8*)(Bs + (wn + nt * 16 + lr) * 64
                                      + (((ks * 4 + quad) ^ rsw) * 8));
      #pragma unroll
      for (int mt = 0; mt < 4; ++mt)
        #pragma unroll
        for (int nt = 0; nt < 4; ++nt)
          acc[mt][nt] = __builtin_amdgcn_mfma_f32_16x16x32_bf16(
              af[mt], bfr[nt], acc[mt][nt], 0, 0, 0);
    }
  }
  #pragma unroll
  for (int mt = 0; mt < 4; ++mt)
    #pragma unroll
    for (int nt = 0; nt < 4; ++nt)
      #pragma unroll
      for (int j = 0; j < 4; ++j) {
        size_t m = m0 + wm + mt * 16 + quad * 4 + j;
        size_t n = n0 + wn + nt * 16 + lr;
        C32[m * DIMC + n] = acc[mt][nt][j];
      }
}

// ---------------- fused flash attention (S^T trick) --------------------------
// grid (64, 16, 4) = (qb, h, b); block 256 = 4 waves; wave owns 16 q-rows
// (q = lane&15). S^T = mfma32(A=K, B=Q) -> C-regs ARE the x16 A-fragment for
// P*V via mfma_f32_16x16x16bf16_1k. Q pre-scaled by 0.125*log2e (exp2 domain).
// T14 staging in 8 NAMED uint4 regs (statically indexed, rule #20).
// LDS: unpadded Ks[128][64], Vs[64][128], XOR-swizzled elem^=((row&7)<<3).
// Denominator via ones-column PV: o[4] = mfma(pf, ones) -- row-sums land in
// [q=quad*4+j] layout, replacing the VALU row-sum + li bookkeeping + shfls.
__global__ __launch_bounds__(256) void attn(ushort* __restrict__ QO,
    const ushort* __restrict__ K, const ushort* __restrict__ Vt) {
  __shared__ __align__(16) ushort Ks[128 * 64];
  __shared__ __align__(16) ushort Vs[64 * 128];
  const int tid  = threadIdx.x;
  const int wave = tid >> 6, lane = tid & 63;
  const int lr = lane & 15, quad = lane >> 4;
  const int b = blockIdx.z, h = blockIdx.y, qb = blockIdx.x;
  const int lsw = (lr & 7) << 3;            // read-side swizzle (elem units)

  // Q B-fragment: B[n=q=lane&15][k=d=quad*8+j]
  bf16x8 bq[2];
  {
    size_t row = (size_t)b * LQ + qb * 64 + wave * 16 + lr;
    const ushort* qp = QO + row * DIMC + h * DHEAD + quad * 8;
    bq[0] = *(const bf16x8*)(qp);
    bq[1] = *(const bf16x8*)(qp + 32);
  }

  // staging geometry (per thread, per chunk i of 4)
  const int krow = tid >> 3, kcol = (tid & 7) * 8;   // K: 128 x 64, 8x16B/row
  const int vrow = tid >> 4, vcol = (tid & 15) * 8;  // V^T: 64 x 128, 16x16B/row
  const int kwsw = (krow & 7) << 3;         // write-side swizzles
  const int vwsw = (vrow & 7) << 3;
  const ushort* Kbase = K  + ((size_t)b * RK) * DIMC + h * DHEAD;
  const ushort* Vbase = Vt + (((size_t)b * HEADS + h) * 64) * RK;

  // T14 prefetch state: named scalars, statically indexed everywhere.
  uint4 kr0, kr1, kr2, kr3, vr0, vr1, vr2, vr3;
#define LOADK(rc_, i_) \
  (*(const uint4*)(Kbase + (size_t)((rc_) * 128 + (i_) * 32 + krow) * DIMC + kcol))
#define LOADV(rc_, i_) \
  (*(const uint4*)(Vbase + (size_t)((i_) * 16 + vrow) * RK + (rc_) * 128 + vcol))
#define ISSUE(rc_) do {                                      \
    kr0 = LOADK(rc_, 0); kr1 = LOADK(rc_, 1);                \
    kr2 = LOADK(rc_, 2); kr3 = LOADK(rc_, 3);                \
    vr0 = LOADV(rc_, 0); vr1 = LOADV(rc_, 1);                \
    vr2 = LOADV(rc_, 2); vr3 = LOADV(rc_, 3);                \
  } while (0)

  ISSUE(0);

  float mi = -1e30f;
  f32x4 o[5] = {};   // o[0..3]: O[q=quad*4+j][dh=n2*16+lr]; o[4]: row-sums

  // ones B-fragment for the denominator tile (bf16 1.0 = 0x3F80)
  const short4v vones = { (short)0x3F80, (short)0x3F80,
                          (short)0x3F80, (short)0x3F80 };

  for (int rc = 0; rc < 4; ++rc) {
    __syncthreads();
    *(uint4*)(Ks + ((((0 * 32 + krow) * 64) + kcol) ^ kwsw)) = kr0;
    *(uint4*)(Ks + ((((1 * 32 + krow) * 64) + kcol) ^ kwsw)) = kr1;
    *(uint4*)(Ks + ((((2 * 32 + krow) * 64) + kcol) ^ kwsw)) = kr2;
    *(uint4*)(Ks + ((((3 * 32 + krow) * 64) + kcol) ^ kwsw)) = kr3;
    *(uint4*)(Vs + ((((0 * 16 + vrow) * 128) + vcol) ^ vwsw)) = vr0;
    *(uint4*)(Vs + ((((1 * 16 + vrow) * 128) + vcol) ^ vwsw)) = vr1;
    *(uint4*)(Vs + ((((2 * 16 + vrow) * 128) + vcol) ^ vwsw)) = vr2;
    *(uint4*)(Vs + ((((3 * 16 + vrow) * 128) + vcol) ^ vwsw)) = vr3;
    __syncthreads();
    if (rc < 3) ISSUE(rc + 1);   // HBM/L2 latency hides under compute below

    // S^T = K Q^T : 8 r-tiles; C-regs: S^T[r=nt*16+quad*4+j][q=lr]
    float s[8][4];
    __builtin_amdgcn_s_setprio(1);
    #pragma unroll
    for (int nt = 0; nt < 8; ++nt) {
      f32x4 acc = {};
      acc = __builtin_amdgcn_mfma_f32_16x16x32_bf16(
          *(const bf16x8*)(Ks + ((((nt * 16 + lr) * 64) + quad * 8) ^ lsw)),
          bq[0], acc, 0, 0, 0);
      acc = __builtin_amdgcn_mfma_f32_16x16x32_bf16(
          *(const bf16x8*)(Ks + ((((nt * 16 + lr) * 64) + quad * 8 + 32) ^ lsw)),
          bq[1], acc, 0, 0, 0);
      #pragma unroll
      for (int j = 0; j < 4; ++j) s[nt][j] = acc[j];   // already exp2-domain
    }
    __builtin_amdgcn_s_setprio(0);

    // online softmax (exp2 domain): one q-row per lane, 32 elems/lane.
    float c0 = s[0][0], c1 = s[0][1], c2 = s[0][2], c3 = s[0][3];
    #pragma unroll
    for (int nt = 1; nt < 8; ++nt) {
      c0 = fmaxf(c0, s[nt][0]); c1 = fmaxf(c1, s[nt][1]);
      c2 = fmaxf(c2, s[nt][2]); c3 = fmaxf(c3, s[nt][3]);
    }
    float cm = fmaxf(fmaxf(c0, c1), fmaxf(c2, c3));
    cm = fmaxf(cm, __shfl_xor(cm, 16));
    cm = fmaxf(cm, __shfl_xor(cm, 32));

    // T13 defer-max: skip O-rescale while the running max grows by <= 8.
    // (o[4] rescales with the others -- denominator stays consistent.)
    if (!__all(cm - mi <= 8.f)) {
      float mnew = fmaxf(mi, cm);
      float alpha = exp2_fast(mi - mnew);
      mi = mnew;
      float a_bc[4];
      #pragma unroll
      for (int j = 0; j < 4; ++j) a_bc[j] = __shfl(alpha, quad * 4 + j, 16);
      #pragma unroll
      for (int n2 = 0; n2 < 5; ++n2)
        #pragma unroll
        for (int j = 0; j < 4; ++j) o[n2][j] *= a_bc[j];
    }

    // exp + bf16 convert (row-sum now done by the MFMA ones-tile)
    short4v pf[8];
    #pragma unroll
    for (int nt = 0; nt < 8; ++nt) {
      float p0 = exp2_fast(s[nt][0] - mi);
      float p1 = exp2_fast(s[nt][1] - mi);
      float p2 = exp2_fast(s[nt][2] - mi);
      float p3 = exp2_fast(s[nt][3] - mi);
      pf[nt][0] = (short)f2bf(p0); pf[nt][1] = (short)f2bf(p1);
      pf[nt][2] = (short)f2bf(p2); pf[nt][3] = (short)f2bf(p3);
    }

    // O += P V : 8 k-steps of 16 x 4 dh-tiles + 1 ones-tile (denominator)
    __builtin_amdgcn_s_setprio(1);
    #pragma unroll
    for (int kt = 0; kt < 8; ++kt) {
      #pragma unroll
      for (int n2 = 0; n2 < 4; ++n2) {
        short4v bv = *(const short4v*)(
            Vs + ((((n2 * 16 + lr) * 128) + kt * 16 + quad * 4) ^ lsw));
        o[n2] = __builtin_amdgcn_mfma_f32_16x16x16bf16_1k(pf[kt], bv, o[n2], 0, 0, 0);
      }
      o[4] = __builtin_amdgcn_mfma_f32_16x16x16bf16_1k(pf[kt], vones, o[4], 0, 0, 0);
    }
    __builtin_amdgcn_s_setprio(0);
  }
#undef LOADK
#undef LOADV
#undef ISSUE

  // normalize + write in-place; o[4][j] is the denominator for row quad*4+j
  #pragma unroll
  for (int n2 = 0; n2 < 4; ++n2)
    #pragma unroll
    for (int j = 0; j < 4; ++j) {
      size_t row = (size_t)b * LQ + qb * 64 + wave * 16 + quad * 4 + j;
      QO[row * DIMC + h * DHEAD + n2 * 16 + lr] = f2bf(o[n2][j] / o[4][j]);
    }
}

// ---------------- launch -----------------------------------------------------
extern "C" void kernel_launch(void* const* d_in, const int* in_sizes, int n_in,
                              void* d_out, int out_size, void* d_ws, size_t ws_size,
                              hipStream_t stream) {
  const float* x   = (const float*)d_in[0];
  const float* ctx = (const float*)d_in[1];

  // d_out scratch (fp32 out buffer = 67 MB; all dead before final GEMM):
  // xb | ctxb | WqT | WkT | WvT | Kw | Vt_g  = 52.4 MB
  ushort* outs = (ushort*)d_out;
  ushort* xb   = outs;                               // 16777216
  ushort* ctxb = outs + (size_t)16777216;            //  2097152
  ushort* WqT  = outs + (size_t)18874368;            //  1048576
  ushort* WkT  = outs + (size_t)19922944;            //  1048576 (WvT contiguous)
  ushort* WvT  = outs + (size_t)20971520;            //  1048576
  ushort* Kw   = outs + (size_t)22020096;            //  2097152
  ushort* Vt_g = outs + (size_t)24117248;            //  2097152

  // ws: Qw (33.5 MB) | WoT (2.1 MB)
  ushort* ws  = (ushort*)d_ws;
  ushort* Qw  = ws;
  ushort* WoT = ws + (size_t)16384 * 1024;

  prep<<<13312, 256, 0, stream>>>(x, ctx, xb, ctxb,
      (const float*)d_in[2], (const float*)d_in[3], (const float*)d_in[4],
      (const float*)d_in[5], WqT, WkT, WvT, WoT);
  gemm_qkv<<<dim3(8, 160), 256, 0, stream>>>(xb, ctxb, WqT, WkT, Qw, Kw, Vt_g);
  attn<<<dim3(LQ / 64, HEADS, BATCH), 256, 0, stream>>>(Qw, Kw, Vt_g);
  gemm_bt<<<dim3(8, 128), 256, 0, stream>>>(Qw, WoT, (float*)d_out);
}